// Round 13
// baseline (425.814 us; speedup 1.0000x reference)
//
#include <hip/hip_runtime.h>

#define BB 64
#define SS 2048
#define FF 256
#define CC 32
#define CH 64   // chunks per sequence (32 steps each)

typedef unsigned u32x2 __attribute__((ext_vector_type(2)));

// Two-result permlane swaps (builtin returns {vdst, vsrc} in distinct regs).
__device__ __forceinline__ void plswap16(int a_in, int& x, int& y) {
#if __has_builtin(__builtin_amdgcn_permlane16_swap)
    u32x2 r = __builtin_amdgcn_permlane16_swap((unsigned)a_in, (unsigned)a_in, false, false);
    x = (int)r[0]; y = (int)r[1];
#else
    int xx = a_in, yy;
    asm volatile("v_mov_b32 %0, %1" : "=v"(yy) : "v"(a_in));
    asm volatile("v_permlane16_swap_b32 %0, %1" : "+v"(xx), "+v"(yy));
    x = xx; y = yy;
#endif
}
__device__ __forceinline__ void plswap32(int a_in, int& x, int& y) {
#if __has_builtin(__builtin_amdgcn_permlane32_swap)
    u32x2 r = __builtin_amdgcn_permlane32_swap((unsigned)a_in, (unsigned)a_in, false, false);
    x = (int)r[0]; y = (int)r[1];
#else
    int xx = a_in, yy;
    asm volatile("v_mov_b32 %0, %1" : "=v"(yy) : "v"(a_in));
    asm volatile("v_permlane32_swap_b32 %0, %1" : "+v"(xx), "+v"(yy));
    x = xx; y = yy;
#endif
}

#if __has_builtin(__builtin_amdgcn_mov_dpp)
#define ROT1(d, s, K) d = __builtin_amdgcn_mov_dpp(s, 0x120 + K, 0xF, 0xF, false)
#else
#define ROT1(d, s, K) d = __builtin_amdgcn_update_dpp(s, s, 0x120 + K, 0xF, 0xF, false)
#endif
#define ROTALL(arr, s) \
    arr[0] = s;        \
    ROT1(arr[1], s, 1);  ROT1(arr[2], s, 2);  ROT1(arr[3], s, 3);  \
    ROT1(arr[4], s, 4);  ROT1(arr[5], s, 5);  ROT1(arr[6], s, 6);  \
    ROT1(arr[7], s, 7);  ROT1(arr[8], s, 8);  ROT1(arr[9], s, 9);  \
    ROT1(arr[10], s, 10); ROT1(arr[11], s, 11); ROT1(arr[12], s, 12); \
    ROT1(arr[13], s, 13); ROT1(arr[14], s, 14); ROT1(arr[15], s, 15)

__device__ __forceinline__ float fmax3_(float a, float b, float c) { return fmaxf(fmaxf(a, b), c); }

// ---------------------------------------------------------------------------
// Kernel 1: emissions GEMM — UNCHANGED (bit-exact).
// ---------------------------------------------------------------------------
__global__ __launch_bounds__(256) void emis_kernel(const float* __restrict__ X,
                                                   const float* __restrict__ W,
                                                   const float* __restrict__ bias,
                                                   float* __restrict__ em) {
    __shared__ __align__(16) float xs[64 * 260];
    __shared__ __align__(16) float wsh[32 * 260];
    const int tid = threadIdx.x;
    const long rowbase = (long)blockIdx.x * 64;

    const float4* Xg = (const float4*)(X + rowbase * FF);
#pragma unroll
    for (int i = 0; i < 16; ++i) {
        int idx = tid + i * 256;
        int r = idx >> 6, c4 = idx & 63;
        *(float4*)&xs[r * 260 + c4 * 4] = Xg[idx];
    }
    const float4* Wg = (const float4*)W;
#pragma unroll
    for (int i = 0; i < 8; ++i) {
        int idx = tid + i * 256;
        int r = idx >> 6, c4 = idx & 63;
        *(float4*)&wsh[r * 260 + c4 * 4] = Wg[idx];
    }
    __syncthreads();

    const int rp = tid >> 3;
    const int cg = (tid & 7) * 4;
    const int r0 = rp * 2, r1 = rp * 2 + 1;
    float acc0[4] = {0.f, 0.f, 0.f, 0.f};
    float acc1[4] = {0.f, 0.f, 0.f, 0.f};

#pragma unroll 4
    for (int k = 0; k < 256; k += 4) {
        float4 xa = *(const float4*)&xs[r0 * 260 + k];
        float4 xb = *(const float4*)&xs[r1 * 260 + k];
#pragma unroll
        for (int jj = 0; jj < 4; ++jj) {
            float4 w = *(const float4*)&wsh[(cg + jj) * 260 + k];
            acc0[jj] = fmaf(xa.x, w.x, acc0[jj]);
            acc0[jj] = fmaf(xa.y, w.y, acc0[jj]);
            acc0[jj] = fmaf(xa.z, w.z, acc0[jj]);
            acc0[jj] = fmaf(xa.w, w.w, acc0[jj]);
            acc1[jj] = fmaf(xb.x, w.x, acc1[jj]);
            acc1[jj] = fmaf(xb.y, w.y, acc1[jj]);
            acc1[jj] = fmaf(xb.z, w.z, acc1[jj]);
            acc1[jj] = fmaf(xb.w, w.w, acc1[jj]);
        }
    }
    float4 b4 = *(const float4*)&bias[cg];
    float4 o0 = make_float4(acc0[0] + b4.x, acc0[1] + b4.y, acc0[2] + b4.z, acc0[3] + b4.w);
    float4 o1 = make_float4(acc1[0] + b4.x, acc1[1] + b4.y, acc1[2] + b4.z, acc1[3] + b4.w);
    *(float4*)&em[(rowbase + r0) * CC + cg] = o0;
    *(float4*)&em[(rowbase + r1) * CC + cg] = o1;
}

// ---------------------------------------------------------------------------
// STEP2X: TWO independent alpha chains interleaved instruction-by-instruction.
// Macro params (vA_/vB_/fA_/fB_) deliberately DISTINCT from asm symbolic names
// ([aA]/[eA]/...) — r12's collision made the preprocessor rewrite "[eA]" ->
// "[eqA[t & 7]]". Per chain the math is exactly STEP2 (bit-identical).
// ---------------------------------------------------------------------------
#define STEP2X_ASM(vA_, vB_, fA_, fB_)                                              \
    do {                                                                            \
        float xA_, bA_, xB_, bB_;                                                   \
        float qA0_, qA1_, qA2_, qA3_, qA4_, qA5_, qA6_, qA7_,                       \
              qA8_, qA9_, qA10_, qA11_, qA12_, qA13_, qA14_, qA15_;                 \
        float qB0_, qB1_, qB2_, qB3_, qB4_, qB5_, qB6_, qB7_,                       \
              qB8_, qB9_, qB10_, qB11_, qB12_, qB13_, qB14_, qB15_;                 \
        asm volatile(                                                               \
            "v_mov_b32 %[xA], %[aA]\n\t"                                            \
            "v_mov_b32 %[xB], %[aB]\n\t"                                            \
            "s_nop 0\n\t"                                                           \
            "v_permlane16_swap_b32 %[xA], %[aA]\n\t"                                \
            "v_permlane16_swap_b32 %[xB], %[aB]\n\t"                                \
            "s_nop 0\n\t"                                                           \
            "v_cndmask_b32 %[bA], %[aA], %[xA], %[m16]\n\t"                         \
            "v_cndmask_b32 %[bB], %[aB], %[xB], %[m16]\n\t"                         \
            "v_add_f32 %[qA0], %[bA], %[t0]\n\t"                                    \
            "v_add_f32 %[qB0], %[bB], %[t0]\n\t"                                    \
            "v_add_f32_dpp %[qA1], %[bA], %[t1] row_ror:1 row_mask:0xf bank_mask:0xf\n\t"  \
            "v_add_f32_dpp %[qB1], %[bB], %[t1] row_ror:1 row_mask:0xf bank_mask:0xf\n\t"  \
            "v_add_f32_dpp %[qA2], %[bA], %[t2] row_ror:2 row_mask:0xf bank_mask:0xf\n\t"  \
            "v_add_f32_dpp %[qB2], %[bB], %[t2] row_ror:2 row_mask:0xf bank_mask:0xf\n\t"  \
            "v_add_f32_dpp %[qA3], %[bA], %[t3] row_ror:3 row_mask:0xf bank_mask:0xf\n\t"  \
            "v_add_f32_dpp %[qB3], %[bB], %[t3] row_ror:3 row_mask:0xf bank_mask:0xf\n\t"  \
            "v_add_f32_dpp %[qA4], %[bA], %[t4] row_ror:4 row_mask:0xf bank_mask:0xf\n\t"  \
            "v_add_f32_dpp %[qB4], %[bB], %[t4] row_ror:4 row_mask:0xf bank_mask:0xf\n\t"  \
            "v_add_f32_dpp %[qA5], %[bA], %[t5] row_ror:5 row_mask:0xf bank_mask:0xf\n\t"  \
            "v_add_f32_dpp %[qB5], %[bB], %[t5] row_ror:5 row_mask:0xf bank_mask:0xf\n\t"  \
            "v_add_f32_dpp %[qA6], %[bA], %[t6] row_ror:6 row_mask:0xf bank_mask:0xf\n\t"  \
            "v_add_f32_dpp %[qB6], %[bB], %[t6] row_ror:6 row_mask:0xf bank_mask:0xf\n\t"  \
            "v_add_f32_dpp %[qA7], %[bA], %[t7] row_ror:7 row_mask:0xf bank_mask:0xf\n\t"  \
            "v_add_f32_dpp %[qB7], %[bB], %[t7] row_ror:7 row_mask:0xf bank_mask:0xf\n\t"  \
            "v_add_f32_dpp %[qA8], %[bA], %[t8] row_ror:8 row_mask:0xf bank_mask:0xf\n\t"  \
            "v_add_f32_dpp %[qB8], %[bB], %[t8] row_ror:8 row_mask:0xf bank_mask:0xf\n\t"  \
            "v_add_f32_dpp %[qA9], %[bA], %[t9] row_ror:9 row_mask:0xf bank_mask:0xf\n\t"  \
            "v_add_f32_dpp %[qB9], %[bB], %[t9] row_ror:9 row_mask:0xf bank_mask:0xf\n\t"  \
            "v_add_f32_dpp %[qA10], %[bA], %[t10] row_ror:10 row_mask:0xf bank_mask:0xf\n\t" \
            "v_add_f32_dpp %[qB10], %[bB], %[t10] row_ror:10 row_mask:0xf bank_mask:0xf\n\t" \
            "v_add_f32_dpp %[qA11], %[bA], %[t11] row_ror:11 row_mask:0xf bank_mask:0xf\n\t" \
            "v_add_f32_dpp %[qB11], %[bB], %[t11] row_ror:11 row_mask:0xf bank_mask:0xf\n\t" \
            "v_add_f32_dpp %[qA12], %[bA], %[t12] row_ror:12 row_mask:0xf bank_mask:0xf\n\t" \
            "v_add_f32_dpp %[qB12], %[bB], %[t12] row_ror:12 row_mask:0xf bank_mask:0xf\n\t" \
            "v_add_f32_dpp %[qA13], %[bA], %[t13] row_ror:13 row_mask:0xf bank_mask:0xf\n\t" \
            "v_add_f32_dpp %[qB13], %[bB], %[t13] row_ror:13 row_mask:0xf bank_mask:0xf\n\t" \
            "v_add_f32_dpp %[qA14], %[bA], %[t14] row_ror:14 row_mask:0xf bank_mask:0xf\n\t" \
            "v_add_f32_dpp %[qB14], %[bB], %[t14] row_ror:14 row_mask:0xf bank_mask:0xf\n\t" \
            "v_add_f32_dpp %[qA15], %[bA], %[t15] row_ror:15 row_mask:0xf bank_mask:0xf\n\t" \
            "v_add_f32_dpp %[qB15], %[bB], %[t15] row_ror:15 row_mask:0xf bank_mask:0xf\n\t" \
            "v_max3_f32 %[qA0], %[qA0], %[qA1], %[qA2]\n\t"                         \
            "v_max3_f32 %[qB0], %[qB0], %[qB1], %[qB2]\n\t"                         \
            "v_max3_f32 %[qA3], %[qA3], %[qA4], %[qA5]\n\t"                         \
            "v_max3_f32 %[qB3], %[qB3], %[qB4], %[qB5]\n\t"                         \
            "v_max3_f32 %[qA6], %[qA6], %[qA7], %[qA8]\n\t"                         \
            "v_max3_f32 %[qB6], %[qB6], %[qB7], %[qB8]\n\t"                         \
            "v_max3_f32 %[qA9], %[qA9], %[qA10], %[qA11]\n\t"                       \
            "v_max3_f32 %[qB9], %[qB9], %[qB10], %[qB11]\n\t"                       \
            "v_max3_f32 %[qA12], %[qA12], %[qA13], %[qA14]\n\t"                     \
            "v_max3_f32 %[qB12], %[qB12], %[qB13], %[qB14]\n\t"                     \
            "v_max3_f32 %[qA0], %[qA0], %[qA3], %[qA6]\n\t"                         \
            "v_max3_f32 %[qB0], %[qB0], %[qB3], %[qB6]\n\t"                         \
            "v_max3_f32 %[qA9], %[qA9], %[qA12], %[qA15]\n\t"                       \
            "v_max3_f32 %[qB9], %[qB9], %[qB12], %[qB15]\n\t"                       \
            "v_max_f32 %[qA0], %[qA0], %[qA9]\n\t"                                  \
            "v_max_f32 %[qB0], %[qB0], %[qB9]\n\t"                                  \
            "v_mov_b32 %[xA], %[qA0]\n\t"                                           \
            "v_mov_b32 %[xB], %[qB0]\n\t"                                           \
            "s_nop 0\n\t"                                                           \
            "v_permlane32_swap_b32 %[xA], %[qA0]\n\t"                               \
            "v_permlane32_swap_b32 %[xB], %[qB0]\n\t"                               \
            "s_nop 0\n\t"                                                           \
            "v_max_f32 %[qA0], %[qA0], %[xA]\n\t"                                   \
            "v_max_f32 %[qB0], %[qB0], %[xB]\n\t"                                   \
            "v_add_f32 %[aA], %[qA0], %[eA]\n\t"                                    \
            "v_add_f32 %[aB], %[qB0], %[eB]\n\t"                                    \
            : [aA] "+v"(vA_), [aB] "+v"(vB_),                                       \
              [xA] "=&v"(xA_), [xB] "=&v"(xB_), [bA] "=&v"(bA_), [bB] "=&v"(bB_),   \
              [qA0] "=&v"(qA0_), [qA1] "=&v"(qA1_), [qA2] "=&v"(qA2_),              \
              [qA3] "=&v"(qA3_), [qA4] "=&v"(qA4_), [qA5] "=&v"(qA5_),              \
              [qA6] "=&v"(qA6_), [qA7] "=&v"(qA7_), [qA8] "=&v"(qA8_),              \
              [qA9] "=&v"(qA9_), [qA10] "=&v"(qA10_), [qA11] "=&v"(qA11_),          \
              [qA12] "=&v"(qA12_), [qA13] "=&v"(qA13_), [qA14] "=&v"(qA14_),        \
              [qA15] "=&v"(qA15_),                                                  \
              [qB0] "=&v"(qB0_), [qB1] "=&v"(qB1_), [qB2] "=&v"(qB2_),              \
              [qB3] "=&v"(qB3_), [qB4] "=&v"(qB4_), [qB5] "=&v"(qB5_),              \
              [qB6] "=&v"(qB6_), [qB7] "=&v"(qB7_), [qB8] "=&v"(qB8_),              \
              [qB9] "=&v"(qB9_), [qB10] "=&v"(qB10_), [qB11] "=&v"(qB11_),          \
              [qB12] "=&v"(qB12_), [qB13] "=&v"(qB13_), [qB14] "=&v"(qB14_),        \
              [qB15] "=&v"(qB15_)                                                   \
            : [eA] "v"(fA_), [eB] "v"(fB_),                                         \
              [t0] "v"(Ti[0]), [t1] "v"(Ti[1]), [t2] "v"(Ti[2]), [t3] "v"(Ti[3]),   \
              [t4] "v"(Ti[4]), [t5] "v"(Ti[5]), [t6] "v"(Ti[6]), [t7] "v"(Ti[7]),   \
              [t8] "v"(Ti[8]), [t9] "v"(Ti[9]), [t10] "v"(Ti[10]),                  \
              [t11] "v"(Ti[11]), [t12] "v"(Ti[12]), [t13] "v"(Ti[13]),              \
              [t14] "v"(Ti[14]), [t15] "v"(Ti[15]),                                 \
              [m16] "s"(mask16));                                                   \
    } while (0)

// ---------------------------------------------------------------------------
// Kernel 2: forward alpha chains — 32 blocks x 1 wave, 2 batches per wave
// (independent register chains, interleaved asm). e via 8-deep global queues;
// alpha stored in-place over em. Per-chain arithmetic bit-identical to r11.
// ---------------------------------------------------------------------------
__global__ __launch_bounds__(64, 1) void viterbi_fwd5(float* __restrict__ em,
                                                      const float* __restrict__ T,
                                                      const float* __restrict__ startT,
                                                      const float* __restrict__ endT,
                                                      float* __restrict__ out) {
    const int l = threadIdx.x;
    const int b0 = blockIdx.x * 2;
    const int b1 = b0 + 1;
    const int j = l & 31;
    const int h = l >> 5;

    int p0, p1;
    plswap16(j, p0, p1);
    const bool c16 = (((p0 >> 4) & 1) == h);
    const int pm = c16 ? p0 : p1;
    int mk[16];
    ROTALL(mk, pm);

    const unsigned long long mask16 = __ballot(c16);

    float Ti[16];
#pragma unroll
    for (int k = 0; k < 16; ++k) Ti[k] = T[mk[k] * CC + j];

    float* ebA = em + (long)b0 * SS * CC;
    float* ebB = em + (long)b1 * SS * CC;

    float eqA[8], eqB[8];
#pragma unroll
    for (int v = 0; v < 8; ++v) { eqA[v] = ebA[v * 32 + j]; eqB[v] = ebB[v * 32 + j]; }

    const float stj = startT[j];
    float aA = stj + eqA[0];
    float aB = stj + eqB[0];
    ebA[j] = aA;
    ebB[j] = aB;
    eqA[0] = ebA[8 * 32 + j];
    eqB[0] = ebB[8 * 32 + j];

    int t = 1;
    for (int g = 0; g < 254; ++g) {
#pragma unroll
        for (int u = 0; u < 8; ++u) {
            STEP2X_ASM(aA, aB, eqA[t & 7], eqB[t & 7]);
            ebA[t * 32 + j] = aA;
            ebB[t * 32 + j] = aB;
            eqA[t & 7] = ebA[(t + 8) * 32 + j];
            eqB[t & 7] = ebB[(t + 8) * 32 + j];
            ++t;
        }
    }
#pragma unroll
    for (int u = 0; u < 7; ++u) {
        STEP2X_ASM(aA, aB, eqA[t & 7], eqB[t & 7]);
        ebA[t * 32 + j] = aA;
        ebB[t * 32 + j] = aB;
        eqA[t & 7] = ebA[(t + 8) * 32 + j];
        eqB[t & 7] = ebB[(t + 8) * 32 + j];
        ++t;
    }
#pragma unroll
    for (int u = 0; u < 8; ++u) {
        STEP2X_ASM(aA, aB, eqA[t & 7], eqB[t & 7]);
        ebA[t * 32 + j] = aA;
        ebB[t * 32 + j] = aB;
        ++t;
    }

    // finals (tie -> lowest j), chain A then chain B
    {
        float v = aA + endT[j];
        int idx = j;
#pragma unroll
        for (int d = 1; d <= 16; d <<= 1) {
            float ovv = __shfl_xor(v, d);
            int   oii = __shfl_xor(idx, d);
            bool c = (ovv > v) || (ovv == v && oii < idx);
            v = c ? ovv : v;
            idx = c ? oii : idx;
        }
        if (l == 0) {
            out[b0] = v;
            out[BB + (long)b0 * SS + (SS - 1)] = (float)idx;
        }
    }
    {
        float v = aB + endT[j];
        int idx = j;
#pragma unroll
        for (int d = 1; d <= 16; d <<= 1) {
            float ovv = __shfl_xor(v, d);
            int   oii = __shfl_xor(idx, d);
            bool c = (ovv > v) || (ovv == v && oii < idx);
            v = c ? ovv : v;
            idx = c ? oii : idx;
        }
        if (l == 0) {
            out[b1] = v;
            out[BB + (long)b1 * SS + (SS - 1)] = (float)idx;
        }
    }
}

// ---------------------------------------------------------------------------
// Kernel 3: bp_compose — CH=64 chunks x 32 steps, exact r6 argmax semantics.
// launch_bounds(64,2): 128-VGPR cap -> NO spills (r11's (64,4) forced scratch).
// ---------------------------------------------------------------------------
__global__ __launch_bounds__(64, 2) void bp_compose(const float* __restrict__ alpha,
                                                    const float* __restrict__ T,
                                                    unsigned* __restrict__ bp,
                                                    unsigned char* __restrict__ G) {
    const int l = threadIdx.x;
    const int j = l & 31;
    const int h = l >> 5;
    const int b = blockIdx.x >> 6;
    const int k = blockIdx.x & 63;

    int p0, p1;
    plswap16(j, p0, p1);
    const bool c16 = (((p0 >> 4) & 1) == h);
    const int pm = c16 ? p0 : p1;
    int mk[16];
    ROTALL(mk, pm);
    int q0p, q1p;
    plswap32(l, q0p, q1p);
    const bool pick0 = (q0p == (l ^ 32));

    float Ti[16];
    unsigned Bk[16];
#pragma unroll
    for (int kk = 0; kk < 16; ++kk) {
        Ti[kk] = T[mk[kk] * CC + j];
        Bk[kk] = 1u << mk[kk];
    }

    const float* A = alpha + (long)b * SS * CC;
    const int u0 = k << 5;

    float aq[8];
#pragma unroll
    for (int v = 0; v < 8; ++v) aq[v] = A[(u0 + v) * CC + j];

    unsigned sr[8];
#pragma unroll
    for (int p = 0; p < 8; ++p) sr[p] = 0u;

#pragma unroll
    for (int g8 = 0; g8 < 4; ++g8) {
#pragma unroll
        for (int v = 0; v < 8; ++v) {
            const int u = g8 * 8 + v;
            float av = aq[v];
            if (g8 < 3) aq[v] = A[(u0 + (g8 + 1) * 8 + v) * CC + j];

            int x, y;
            plswap16(__float_as_int(av), x, y);
            int base = c16 ? x : y;
            int rot[16];
            ROTALL(rot, base);
            float s[16];
#pragma unroll
            for (int kk = 0; kk < 16; ++kk) s[kk] = __int_as_float(rot[kk]) + Ti[kk];

            float m0 = fmax3_(s[0], s[1], s[2]);
            float m1 = fmax3_(s[3], s[4], s[5]);
            float m2 = fmax3_(s[6], s[7], s[8]);
            float m3 = fmax3_(s[9], s[10], s[11]);
            float m4 = fmax3_(s[12], s[13], s[14]);
            float mv = fmaxf(fmax3_(m0, m1, m2), fmax3_(m3, m4, s[15]));

            int xm, ym;
            plswap32(__float_as_int(mv), xm, ym);
            float ov = __int_as_float(pick0 ? xm : ym);
            float gv = fmaxf(mv, ov);

            unsigned c0 = (s[0] == gv) ? Bk[0] : 0u,   c1 = (s[1] == gv) ? Bk[1] : 0u;
            unsigned c2 = (s[2] == gv) ? Bk[2] : 0u,   c3 = (s[3] == gv) ? Bk[3] : 0u;
            unsigned c4 = (s[4] == gv) ? Bk[4] : 0u,   c5 = (s[5] == gv) ? Bk[5] : 0u;
            unsigned c6 = (s[6] == gv) ? Bk[6] : 0u,   c7 = (s[7] == gv) ? Bk[7] : 0u;
            unsigned c8 = (s[8] == gv) ? Bk[8] : 0u,   c9 = (s[9] == gv) ? Bk[9] : 0u;
            unsigned c10 = (s[10] == gv) ? Bk[10] : 0u, c11 = (s[11] == gv) ? Bk[11] : 0u;
            unsigned c12 = (s[12] == gv) ? Bk[12] : 0u, c13 = (s[13] == gv) ? Bk[13] : 0u;
            unsigned c14 = (s[14] == gv) ? Bk[14] : 0u, c15 = (s[15] == gv) ? Bk[15] : 0u;
            unsigned msk = ((c0 | c1 | c2) | (c3 | c4 | c5)) |
                           ((c6 | c7 | c8) | (c9 | c10 | c11)) |
                           ((c12 | c13 | c14) | c15);

            int xk, yk;
            plswap32((int)msk, xk, yk);
            unsigned om = (unsigned)(pick0 ? xk : yk);
            int wi = __builtin_ctz(msk | om);

            if (u == 31 && k == CH - 1) wi = j;   // bp slot 2047 = identity
            sr[u >> 2] |= (unsigned)wi << ((u & 3) * 8);
        }
    }

#pragma unroll
    for (int p = 0; p < 8; ++p)
        bp[((unsigned)(8 * k + p) * BB + b) * CC + j] = sr[p];

    int g = j;
#pragma unroll
    for (int rel = 31; rel >= 0; --rel) {
        unsigned dw = (unsigned)__builtin_amdgcn_ds_bpermute((g | (l & 32)) << 2,
                                                             (int)sr[rel >> 2]);
        g = (int)((dw >> ((rel & 3) * 8)) & 31u);
    }
    G[(b * CH + k) * 32 + j] = (unsigned char)g;
}

// ---------------------------------------------------------------------------
// Kernel 4: bt_scan — 2 blocks x 32 batches; G staged in LDS (64 KB/block).
// ---------------------------------------------------------------------------
__global__ __launch_bounds__(64) void bt_scan(const unsigned char* __restrict__ G,
                                              const float* __restrict__ out,
                                              int* __restrict__ tagB) {
    __shared__ unsigned char Gs[32 * CH * 32];
    const int l = threadIdx.x;
    const int bbase = blockIdx.x * 32;
    const float4* Gg = (const float4*)(G + (size_t)bbase * CH * 32);
    float4* Gls = (float4*)Gs;
#pragma unroll
    for (int i = 0; i < 64; ++i) Gls[l + i * 64] = Gg[l + i * 64];
    __syncthreads();

    if (l < 32) {
        const int b = bbase + l;
        int cur = (int)out[BB + (long)b * SS + (SS - 1)];
        for (int k = CH - 1; k >= 0; --k) {
            cur = Gs[(l * CH + k) * 32 + cur];
            tagB[b * CH + k] = cur;
        }
    }
}

// ---------------------------------------------------------------------------
// Kernel 5: bt_emit — 4096 blocks, each re-walks its 32-step chunk.
// ---------------------------------------------------------------------------
__global__ __launch_bounds__(64, 4) void bt_emit(const unsigned* __restrict__ bp,
                                                 const int* __restrict__ tagB,
                                                 const float* __restrict__ outR,
                                                 float* __restrict__ out) {
    const int l = threadIdx.x;
    const int b = blockIdx.x >> 6;
    const int k = blockIdx.x & 63;

    unsigned sr[8];
#pragma unroll
    for (int p = 0; p < 8; ++p) sr[p] = bp[((unsigned)(8 * k + p) * BB + b) * CC + (l & 31)];

    int start = (k == CH - 1) ? (int)outR[BB + (long)b * SS + (SS - 1)]
                              : tagB[b * CH + k + 1];
    int g = start, cap = start;
#pragma unroll
    for (int rel = 31; rel >= 0; --rel) {
        unsigned dw = (unsigned)__builtin_amdgcn_ds_bpermute((g | (l & 32)) << 2,
                                                             (int)sr[rel >> 2]);
        g = (int)((dw >> ((rel & 3) * 8)) & 31u);
        cap = (l == rel) ? g : cap;
    }
    if (l < 32) out[BB + (long)b * SS + k * 32 + l] = (float)cap;
}

// ---------------------------------------------------------------------------
extern "C" void kernel_launch(void* const* d_in, const int* in_sizes, int n_in,
                              void* d_out, int out_size, void* d_ws, size_t ws_size,
                              hipStream_t stream) {
    const float* X      = (const float*)d_in[0];
    const float* W      = (const float*)d_in[1];
    const float* bias   = (const float*)d_in[2];
    const float* T      = (const float*)d_in[3];
    const float* startT = (const float*)d_in[4];
    const float* endT   = (const float*)d_in[5];
    float* out = (float*)d_out;

    float*    em = (float*)d_ws;                                        // 16 MB (e -> alpha in-place)
    unsigned* bp = (unsigned*)((char*)d_ws + (size_t)BB * SS * CC * 4); // 4 MB @ 16 MB
    unsigned char* G    = (unsigned char*)d_ws + (20u << 20);           // 128 KB @ 20 MB
    int*           tagB = (int*)((char*)d_ws + (20u << 20) + 131072);   // 16 KB

    emis_kernel<<<(BB * SS) / 64, 256, 0, stream>>>(X, W, bias, em);
    viterbi_fwd5<<<BB / 2, 64, 0, stream>>>(em, T, startT, endT, out);
    bp_compose<<<BB * CH, 64, 0, stream>>>(em, T, bp, G);
    bt_scan<<<2, 64, 0, stream>>>(G, out, tagB);
    bt_emit<<<BB * CH, 64, 0, stream>>>(bp, tagB, out, out);
}

// Round 14
// 260.146 us; speedup vs baseline: 1.6368x; 1.6368x over previous
//
#include <hip/hip_runtime.h>

#define BB 64
#define SS 2048
#define FF 256
#define CC 32
#define CH 64   // chunks per sequence (32 steps each)

typedef unsigned u32x2 __attribute__((ext_vector_type(2)));

// Two-result permlane swaps (builtin returns {vdst, vsrc} in distinct regs).
__device__ __forceinline__ void plswap16(int a_in, int& x, int& y) {
#if __has_builtin(__builtin_amdgcn_permlane16_swap)
    u32x2 r = __builtin_amdgcn_permlane16_swap((unsigned)a_in, (unsigned)a_in, false, false);
    x = (int)r[0]; y = (int)r[1];
#else
    int xx = a_in, yy;
    asm volatile("v_mov_b32 %0, %1" : "=v"(yy) : "v"(a_in));
    asm volatile("v_permlane16_swap_b32 %0, %1" : "+v"(xx), "+v"(yy));
    x = xx; y = yy;
#endif
}
__device__ __forceinline__ void plswap32(int a_in, int& x, int& y) {
#if __has_builtin(__builtin_amdgcn_permlane32_swap)
    u32x2 r = __builtin_amdgcn_permlane32_swap((unsigned)a_in, (unsigned)a_in, false, false);
    x = (int)r[0]; y = (int)r[1];
#else
    int xx = a_in, yy;
    asm volatile("v_mov_b32 %0, %1" : "=v"(yy) : "v"(a_in));
    asm volatile("v_permlane32_swap_b32 %0, %1" : "+v"(xx), "+v"(yy));
    x = xx; y = yy;
#endif
}

#if __has_builtin(__builtin_amdgcn_mov_dpp)
#define ROT1(d, s, K) d = __builtin_amdgcn_mov_dpp(s, 0x120 + K, 0xF, 0xF, false)
#else
#define ROT1(d, s, K) d = __builtin_amdgcn_update_dpp(s, s, 0x120 + K, 0xF, 0xF, false)
#endif
#define ROTALL(arr, s) \
    arr[0] = s;        \
    ROT1(arr[1], s, 1);  ROT1(arr[2], s, 2);  ROT1(arr[3], s, 3);  \
    ROT1(arr[4], s, 4);  ROT1(arr[5], s, 5);  ROT1(arr[6], s, 6);  \
    ROT1(arr[7], s, 7);  ROT1(arr[8], s, 8);  ROT1(arr[9], s, 9);  \
    ROT1(arr[10], s, 10); ROT1(arr[11], s, 11); ROT1(arr[12], s, 12); \
    ROT1(arr[13], s, 13); ROT1(arr[14], s, 14); ROT1(arr[15], s, 15)

__device__ __forceinline__ float fmax3_(float a, float b, float c) { return fmaxf(fmaxf(a, b), c); }

// ---------------------------------------------------------------------------
// Kernel 1: emissions GEMM v2.
//  * X NOT staged (per-thread global stream; 8 lanes/row broadcast via L1).
//  * Only W in LDS (33 KB) -> 4 blocks/CU = 4 waves/SIMD TLP (was 1).
//  * Thread cols {c, c+8, c+16, c+24}: the 8 W-rows read per instruction span
//    all 8 bank-quads (stride 260 dwords, 260%8=4) -> conflict-free.
//  * FMA order per output unchanged (k ascending, x/y/z/w) -> bit-identical.
// ---------------------------------------------------------------------------
__global__ __launch_bounds__(256) void emis_kernel(const float* __restrict__ X,
                                                   const float* __restrict__ W,
                                                   const float* __restrict__ bias,
                                                   float* __restrict__ em) {
    __shared__ __align__(16) float wsh[32 * 260];
    const int tid = threadIdx.x;
    const long rowbase = (long)blockIdx.x * 64;

    const float4* Wg = (const float4*)W;
#pragma unroll
    for (int i = 0; i < 8; ++i) {
        int idx = tid + i * 256;          // 0..2047 float4 slots (32 rows x 64)
        int r = idx >> 6, c4 = idx & 63;
        *(float4*)&wsh[r * 260 + c4 * 4] = Wg[idx];
    }
    __syncthreads();

    const int rp = tid >> 3;              // 0..31 -> rows 2rp, 2rp+1
    const int cgp = tid & 7;              // cols {cgp, cgp+8, cgp+16, cgp+24}
    const long r0 = rowbase + 2 * rp, r1 = r0 + 1;
    const float4* X0 = (const float4*)(X + r0 * FF);
    const float4* X1 = (const float4*)(X + r1 * FF);

    float acc0[4] = {0.f, 0.f, 0.f, 0.f};
    float acc1[4] = {0.f, 0.f, 0.f, 0.f};

#pragma unroll 8
    for (int k4 = 0; k4 < 64; ++k4) {
        float4 xa = X0[k4];
        float4 xb = X1[k4];
#pragma unroll
        for (int jj = 0; jj < 4; ++jj) {
            float4 w = *(const float4*)&wsh[(cgp + 8 * jj) * 260 + k4 * 4];
            acc0[jj] = fmaf(xa.x, w.x, acc0[jj]);
            acc0[jj] = fmaf(xa.y, w.y, acc0[jj]);
            acc0[jj] = fmaf(xa.z, w.z, acc0[jj]);
            acc0[jj] = fmaf(xa.w, w.w, acc0[jj]);
            acc1[jj] = fmaf(xb.x, w.x, acc1[jj]);
            acc1[jj] = fmaf(xb.y, w.y, acc1[jj]);
            acc1[jj] = fmaf(xb.z, w.z, acc1[jj]);
            acc1[jj] = fmaf(xb.w, w.w, acc1[jj]);
        }
    }
#pragma unroll
    for (int jj = 0; jj < 4; ++jj) {
        int c = cgp + 8 * jj;
        float bj = bias[c];
        em[r0 * CC + c] = acc0[jj] + bj;
        em[r1 * CC + c] = acc1[jj] + bj;
    }
}

// ---------------------------------------------------------------------------
// STEP2: r11's proven asm step (trimmed tail: mov+swap32+max — exact since
// {own,partner} under commutative fmax covers the global max).
// ---------------------------------------------------------------------------
#define STEP2_ASM(avar, evar)                                                       \
    do {                                                                            \
        float x_, b_, q0_, q1_, q2_, q3_, q4_, q5_, q6_, q7_,                       \
              q8_, q9_, q10_, q11_, q12_, q13_, q14_, q15_;                         \
        asm volatile(                                                               \
            "v_mov_b32 %[x], %[aa]\n\t"                                             \
            "s_nop 1\n\t"                                                           \
            "v_permlane16_swap_b32 %[x], %[aa]\n\t"                                 \
            "s_nop 0\n\t"                                                           \
            "v_cndmask_b32 %[bb], %[aa], %[x], %[m16]\n\t"                          \
            "s_nop 1\n\t"                                                           \
            "v_add_f32 %[q0], %[bb], %[t0]\n\t"                                     \
            "v_add_f32_dpp %[q1], %[bb], %[t1] row_ror:1 row_mask:0xf bank_mask:0xf\n\t"  \
            "v_add_f32_dpp %[q2], %[bb], %[t2] row_ror:2 row_mask:0xf bank_mask:0xf\n\t"  \
            "v_add_f32_dpp %[q3], %[bb], %[t3] row_ror:3 row_mask:0xf bank_mask:0xf\n\t"  \
            "v_add_f32_dpp %[q4], %[bb], %[t4] row_ror:4 row_mask:0xf bank_mask:0xf\n\t"  \
            "v_add_f32_dpp %[q5], %[bb], %[t5] row_ror:5 row_mask:0xf bank_mask:0xf\n\t"  \
            "v_add_f32_dpp %[q6], %[bb], %[t6] row_ror:6 row_mask:0xf bank_mask:0xf\n\t"  \
            "v_add_f32_dpp %[q7], %[bb], %[t7] row_ror:7 row_mask:0xf bank_mask:0xf\n\t"  \
            "v_add_f32_dpp %[q8], %[bb], %[t8] row_ror:8 row_mask:0xf bank_mask:0xf\n\t"  \
            "v_add_f32_dpp %[q9], %[bb], %[t9] row_ror:9 row_mask:0xf bank_mask:0xf\n\t"  \
            "v_add_f32_dpp %[q10], %[bb], %[t10] row_ror:10 row_mask:0xf bank_mask:0xf\n\t" \
            "v_add_f32_dpp %[q11], %[bb], %[t11] row_ror:11 row_mask:0xf bank_mask:0xf\n\t" \
            "v_add_f32_dpp %[q12], %[bb], %[t12] row_ror:12 row_mask:0xf bank_mask:0xf\n\t" \
            "v_add_f32_dpp %[q13], %[bb], %[t13] row_ror:13 row_mask:0xf bank_mask:0xf\n\t" \
            "v_add_f32_dpp %[q14], %[bb], %[t14] row_ror:14 row_mask:0xf bank_mask:0xf\n\t" \
            "v_add_f32_dpp %[q15], %[bb], %[t15] row_ror:15 row_mask:0xf bank_mask:0xf\n\t" \
            "v_max3_f32 %[q0], %[q0], %[q1], %[q2]\n\t"                             \
            "v_max3_f32 %[q3], %[q3], %[q4], %[q5]\n\t"                             \
            "v_max3_f32 %[q6], %[q6], %[q7], %[q8]\n\t"                             \
            "v_max3_f32 %[q9], %[q9], %[q10], %[q11]\n\t"                           \
            "v_max3_f32 %[q12], %[q12], %[q13], %[q14]\n\t"                         \
            "v_max3_f32 %[q0], %[q0], %[q3], %[q6]\n\t"                             \
            "v_max3_f32 %[q9], %[q9], %[q12], %[q15]\n\t"                           \
            "v_max_f32 %[q0], %[q0], %[q9]\n\t"                                     \
            "v_mov_b32 %[x], %[q0]\n\t"                                             \
            "s_nop 1\n\t"                                                           \
            "v_permlane32_swap_b32 %[x], %[q0]\n\t"                                 \
            "s_nop 0\n\t"                                                           \
            "v_max_f32 %[q0], %[q0], %[x]\n\t"                                      \
            "v_add_f32 %[aa], %[q0], %[ee]\n\t"                                     \
            : [aa] "+v"(avar), [x] "=&v"(x_), [bb] "=&v"(b_),                       \
              [q0] "=&v"(q0_), [q1] "=&v"(q1_), [q2] "=&v"(q2_), [q3] "=&v"(q3_),   \
              [q4] "=&v"(q4_), [q5] "=&v"(q5_), [q6] "=&v"(q6_), [q7] "=&v"(q7_),   \
              [q8] "=&v"(q8_), [q9] "=&v"(q9_), [q10] "=&v"(q10_),                  \
              [q11] "=&v"(q11_), [q12] "=&v"(q12_), [q13] "=&v"(q13_),              \
              [q14] "=&v"(q14_), [q15] "=&v"(q15_)                                  \
            : [ee] "v"(evar), [t0] "v"(Ti[0]), [t1] "v"(Ti[1]), [t2] "v"(Ti[2]),    \
              [t3] "v"(Ti[3]), [t4] "v"(Ti[4]), [t5] "v"(Ti[5]), [t6] "v"(Ti[6]),   \
              [t7] "v"(Ti[7]), [t8] "v"(Ti[8]), [t9] "v"(Ti[9]), [t10] "v"(Ti[10]), \
              [t11] "v"(Ti[11]), [t12] "v"(Ti[12]), [t13] "v"(Ti[13]),              \
              [t14] "v"(Ti[14]), [t15] "v"(Ti[15]),                                 \
              [m16] "s"(mask16));                                                   \
    } while (0)

// ---------------------------------------------------------------------------
// Kernel 2: forward alpha chain — r11's proven fwd4 (64 blocks x 1 wave).
// e via 8-deep global register queue; alpha stored in-place over em.
// ---------------------------------------------------------------------------
__global__ __launch_bounds__(64, 1) void viterbi_fwd4(float* __restrict__ em,
                                                      const float* __restrict__ T,
                                                      const float* __restrict__ startT,
                                                      const float* __restrict__ endT,
                                                      float* __restrict__ out) {
    const int l = threadIdx.x;
    const int b = blockIdx.x;
    const int j = l & 31;
    const int h = l >> 5;

    int p0, p1;
    plswap16(j, p0, p1);
    const bool c16 = (((p0 >> 4) & 1) == h);
    const int pm = c16 ? p0 : p1;
    int mk[16];
    ROTALL(mk, pm);

    const unsigned long long mask16 = __ballot(c16);

    float Ti[16];
#pragma unroll
    for (int k = 0; k < 16; ++k) Ti[k] = T[mk[k] * CC + j];

    float* eb = em + (long)b * SS * CC;

    float eq[8];
#pragma unroll
    for (int v = 0; v < 8; ++v) eq[v] = eb[v * 32 + j];

    float a = startT[j] + eq[0];           // alpha_0
    eb[j] = a;
    eq[0] = eb[8 * 32 + j];

    int t = 1;
    for (int g = 0; g < 254; ++g) {
#pragma unroll
        for (int u = 0; u < 8; ++u) {
            STEP2_ASM(a, eq[t & 7]);
            eb[t * 32 + j] = a;
            eq[t & 7] = eb[(t + 8) * 32 + j];
            ++t;
        }
    }
#pragma unroll
    for (int u = 0; u < 7; ++u) {
        STEP2_ASM(a, eq[t & 7]);
        eb[t * 32 + j] = a;
        eq[t & 7] = eb[(t + 8) * 32 + j];
        ++t;
    }
#pragma unroll
    for (int u = 0; u < 8; ++u) {
        STEP2_ASM(a, eq[t & 7]);
        eb[t * 32 + j] = a;
        ++t;
    }

    float v = a + endT[j];
    int idx = j;
#pragma unroll
    for (int d = 1; d <= 16; d <<= 1) {
        float ovv = __shfl_xor(v, d);
        int   oii = __shfl_xor(idx, d);
        bool c = (ovv > v) || (ovv == v && oii < idx);
        v = c ? ovv : v;
        idx = c ? oii : idx;
    }
    if (l == 0) {
        out[b] = v;
        out[BB + (long)b * SS + (SS - 1)] = (float)idx;
    }
}

// ---------------------------------------------------------------------------
// Kernel 3: bp_compose — CH=64 chunks x 32 steps, exact argmax semantics.
// launch_bounds(64,2): no spills.
// ---------------------------------------------------------------------------
__global__ __launch_bounds__(64, 2) void bp_compose(const float* __restrict__ alpha,
                                                    const float* __restrict__ T,
                                                    unsigned* __restrict__ bp,
                                                    unsigned char* __restrict__ G) {
    const int l = threadIdx.x;
    const int j = l & 31;
    const int h = l >> 5;
    const int b = blockIdx.x >> 6;
    const int k = blockIdx.x & 63;

    int p0, p1;
    plswap16(j, p0, p1);
    const bool c16 = (((p0 >> 4) & 1) == h);
    const int pm = c16 ? p0 : p1;
    int mk[16];
    ROTALL(mk, pm);
    int q0p, q1p;
    plswap32(l, q0p, q1p);
    const bool pick0 = (q0p == (l ^ 32));

    float Ti[16];
    unsigned Bk[16];
#pragma unroll
    for (int kk = 0; kk < 16; ++kk) {
        Ti[kk] = T[mk[kk] * CC + j];
        Bk[kk] = 1u << mk[kk];
    }

    const float* A = alpha + (long)b * SS * CC;
    const int u0 = k << 5;

    float aq[8];
#pragma unroll
    for (int v = 0; v < 8; ++v) aq[v] = A[(u0 + v) * CC + j];

    unsigned sr[8];
#pragma unroll
    for (int p = 0; p < 8; ++p) sr[p] = 0u;

#pragma unroll
    for (int g8 = 0; g8 < 4; ++g8) {
#pragma unroll
        for (int v = 0; v < 8; ++v) {
            const int u = g8 * 8 + v;
            float av = aq[v];
            if (g8 < 3) aq[v] = A[(u0 + (g8 + 1) * 8 + v) * CC + j];

            int x, y;
            plswap16(__float_as_int(av), x, y);
            int base = c16 ? x : y;
            int rot[16];
            ROTALL(rot, base);
            float s[16];
#pragma unroll
            for (int kk = 0; kk < 16; ++kk) s[kk] = __int_as_float(rot[kk]) + Ti[kk];

            float m0 = fmax3_(s[0], s[1], s[2]);
            float m1 = fmax3_(s[3], s[4], s[5]);
            float m2 = fmax3_(s[6], s[7], s[8]);
            float m3 = fmax3_(s[9], s[10], s[11]);
            float m4 = fmax3_(s[12], s[13], s[14]);
            float mv = fmaxf(fmax3_(m0, m1, m2), fmax3_(m3, m4, s[15]));

            int xm, ym;
            plswap32(__float_as_int(mv), xm, ym);
            float ov = __int_as_float(pick0 ? xm : ym);
            float gv = fmaxf(mv, ov);

            unsigned c0 = (s[0] == gv) ? Bk[0] : 0u,   c1 = (s[1] == gv) ? Bk[1] : 0u;
            unsigned c2 = (s[2] == gv) ? Bk[2] : 0u,   c3 = (s[3] == gv) ? Bk[3] : 0u;
            unsigned c4 = (s[4] == gv) ? Bk[4] : 0u,   c5 = (s[5] == gv) ? Bk[5] : 0u;
            unsigned c6 = (s[6] == gv) ? Bk[6] : 0u,   c7 = (s[7] == gv) ? Bk[7] : 0u;
            unsigned c8 = (s[8] == gv) ? Bk[8] : 0u,   c9 = (s[9] == gv) ? Bk[9] : 0u;
            unsigned c10 = (s[10] == gv) ? Bk[10] : 0u, c11 = (s[11] == gv) ? Bk[11] : 0u;
            unsigned c12 = (s[12] == gv) ? Bk[12] : 0u, c13 = (s[13] == gv) ? Bk[13] : 0u;
            unsigned c14 = (s[14] == gv) ? Bk[14] : 0u, c15 = (s[15] == gv) ? Bk[15] : 0u;
            unsigned msk = ((c0 | c1 | c2) | (c3 | c4 | c5)) |
                           ((c6 | c7 | c8) | (c9 | c10 | c11)) |
                           ((c12 | c13 | c14) | c15);

            int xk, yk;
            plswap32((int)msk, xk, yk);
            unsigned om = (unsigned)(pick0 ? xk : yk);
            int wi = __builtin_ctz(msk | om);

            if (u == 31 && k == CH - 1) wi = j;   // bp slot 2047 = identity
            sr[u >> 2] |= (unsigned)wi << ((u & 3) * 8);
        }
    }

#pragma unroll
    for (int p = 0; p < 8; ++p)
        bp[((unsigned)(8 * k + p) * BB + b) * CC + j] = sr[p];

    int g = j;
#pragma unroll
    for (int rel = 31; rel >= 0; --rel) {
        unsigned dw = (unsigned)__builtin_amdgcn_ds_bpermute((g | (l & 32)) << 2,
                                                             (int)sr[rel >> 2]);
        g = (int)((dw >> ((rel & 3) * 8)) & 31u);
    }
    G[(b * CH + k) * 32 + j] = (unsigned char)g;
}

// ---------------------------------------------------------------------------
// Kernel 4: bt_scan — 2 blocks x 32 batches; G staged in LDS (64 KB/block).
// ---------------------------------------------------------------------------
__global__ __launch_bounds__(64) void bt_scan(const unsigned char* __restrict__ G,
                                              const float* __restrict__ out,
                                              int* __restrict__ tagB) {
    __shared__ unsigned char Gs[32 * CH * 32];
    const int l = threadIdx.x;
    const int bbase = blockIdx.x * 32;
    const float4* Gg = (const float4*)(G + (size_t)bbase * CH * 32);
    float4* Gls = (float4*)Gs;
#pragma unroll
    for (int i = 0; i < 64; ++i) Gls[l + i * 64] = Gg[l + i * 64];
    __syncthreads();

    if (l < 32) {
        const int b = bbase + l;
        int cur = (int)out[BB + (long)b * SS + (SS - 1)];
        for (int k = CH - 1; k >= 0; --k) {
            cur = Gs[(l * CH + k) * 32 + cur];
            tagB[b * CH + k] = cur;
        }
    }
}

// ---------------------------------------------------------------------------
// Kernel 5: bt_emit — 4096 blocks, each re-walks its 32-step chunk.
// ---------------------------------------------------------------------------
__global__ __launch_bounds__(64, 4) void bt_emit(const unsigned* __restrict__ bp,
                                                 const int* __restrict__ tagB,
                                                 const float* __restrict__ outR,
                                                 float* __restrict__ out) {
    const int l = threadIdx.x;
    const int b = blockIdx.x >> 6;
    const int k = blockIdx.x & 63;

    unsigned sr[8];
#pragma unroll
    for (int p = 0; p < 8; ++p) sr[p] = bp[((unsigned)(8 * k + p) * BB + b) * CC + (l & 31)];

    int start = (k == CH - 1) ? (int)outR[BB + (long)b * SS + (SS - 1)]
                              : tagB[b * CH + k + 1];
    int g = start, cap = start;
#pragma unroll
    for (int rel = 31; rel >= 0; --rel) {
        unsigned dw = (unsigned)__builtin_amdgcn_ds_bpermute((g | (l & 32)) << 2,
                                                             (int)sr[rel >> 2]);
        g = (int)((dw >> ((rel & 3) * 8)) & 31u);
        cap = (l == rel) ? g : cap;
    }
    if (l < 32) out[BB + (long)b * SS + k * 32 + l] = (float)cap;
}

// ---------------------------------------------------------------------------
extern "C" void kernel_launch(void* const* d_in, const int* in_sizes, int n_in,
                              void* d_out, int out_size, void* d_ws, size_t ws_size,
                              hipStream_t stream) {
    const float* X      = (const float*)d_in[0];
    const float* W      = (const float*)d_in[1];
    const float* bias   = (const float*)d_in[2];
    const float* T      = (const float*)d_in[3];
    const float* startT = (const float*)d_in[4];
    const float* endT   = (const float*)d_in[5];
    float* out = (float*)d_out;

    float*    em = (float*)d_ws;                                        // 16 MB (e -> alpha in-place)
    unsigned* bp = (unsigned*)((char*)d_ws + (size_t)BB * SS * CC * 4); // 4 MB @ 16 MB
    unsigned char* G    = (unsigned char*)d_ws + (20u << 20);           // 128 KB @ 20 MB
    int*           tagB = (int*)((char*)d_ws + (20u << 20) + 131072);   // 16 KB

    emis_kernel<<<(BB * SS) / 64, 256, 0, stream>>>(X, W, bias, em);
    viterbi_fwd4<<<BB, 64, 0, stream>>>(em, T, startT, endT, out);
    bp_compose<<<BB * CH, 64, 0, stream>>>(em, T, bp, G);
    bt_scan<<<2, 64, 0, stream>>>(G, out, tagB);
    bt_emit<<<BB * CH, 64, 0, stream>>>(bp, tagB, out, out);
}